// Round 5
// baseline (107.240 us; speedup 1.0000x reference)
//
#include <hip/hip_runtime.h>

#define PI_D 3.14159265358979323846
#define PI_F 3.14159265358979323846f

// ---- workspace layout (floats) ----
// V01 @ 2359296 : 524288   V02 @ 2883584 : 262144   V12 @ 3145728 : 131072
// P1p @ 3276800 : 128      P2p @ 3276928 : 64
// T01 @ 3276992 : 256      T02 @ 3277248 : 256      T12 @ 3277504 : 128

// Dirichlet tap, f64 (computed in k_front; k_main loads precomputed tables).
// Analytically: Rl[0] = 1 and Rl[t] = 0 for t % s == 0 (t != 0, s = n1/n2).
__device__ inline float rtab_val(int n, int m2, int t) {
  if (t == 0) return 1.0f;
  double th = PI_D * (double)t / (double)n;
  double v = sin(th * (double)(m2 - 1)) / sin(th) + cos(th * (double)m2);
  return (float)(v / (double)m2);
}

// k_front: bid 0..191 P partials; 192..319 V01 (odd cols computed, even cols
// exact X1 copies; bid 192 writes T01); 320..447 V02 (bid 320 writes T02);
// 448..511 V12 (bid 448 writes T12); 512 zeroes out (NO hipMemsetAsync -- a
// 21 KB fillBufferAligned was measured at ~43 us, as costly as the 256 MB
// workspace poison; in-kernel zeroing is ~free).
__global__ __launch_bounds__(256) void k_front(
    const float* __restrict__ X0, const float* __restrict__ X1,
    const float* __restrict__ X2, float* __restrict__ P1p,
    float* __restrict__ P2p, float* __restrict__ V01, float* __restrict__ V02,
    float* __restrict__ V12, float* __restrict__ T01, float* __restrict__ T02,
    float* __restrict__ T12, float* __restrict__ out) {
  __shared__ float fsm[2304];
  int bid = blockIdx.x;
  int t = threadIdx.x;
  if (bid == 512) {
    for (int i = t; i < 5376; i += 256) out[i] = 0.f;
    return;
  }
  if (bid < 192) {
    // ---- P partials ----
    const float* X; float* P; int lg, nsp, idx0;
    if (bid < 128) { X = X1; P = P1p; lg = 7; nsp = 8; idx0 = bid; }
    else           { X = X2; P = P2p; lg = 6; nsp = 4; idx0 = bid - 128; }
    int ch = idx0 / nsp, split = idx0 % nsp;
    int n = 1 << lg;
    int total = n * n;
    int chunk = total / nsp;
    int b0 = split * chunk;
    const float* x = X + (size_t)ch * total + b0;
    float s = 0.f;
    for (int i = t; i < chunk; i += 256) {
      int idx = b0 + i;
      float v = x[i];
      s += (((idx >> lg) ^ idx) & 1) ? -v : v;
    }
#pragma unroll
    for (int off = 32; off > 0; off >>= 1) s += __shfl_down(s, off, 64);
    __shared__ float red[4];
    if ((t & 63) == 0) red[t >> 6] = s;
    __syncthreads();
    if (t == 0) P[ch * nsp + split] = red[0] + red[1] + red[2] + red[3];
    return;
  }
  if (bid < 320) {
    // ---- V01: compute odd columns only; even columns copy X1 ----
    int idx = bid - 192;
    int ch = idx >> 3, nxg = (idx & 7) * 16;
    float* Rl = fsm;
    float* Xs = fsm + 256;
    for (int i = t; i < 256; i += 256) Rl[i] = rtab_val(256, 128, i);
    const float4* xch4 =
        (const float4*)(X1 + (size_t)ch * 16384 + (size_t)nxg * 128);
    for (int i = t; i < 512; i += 256) ((float4*)Xs)[i] = xch4[i];
    __syncthreads();
    if (idx == 0)
      for (int i = t; i < 256; i += 256) T01[i] = Rl[i];
    float* vch = V01 + (size_t)ch * 128 * 256;
    for (int i = t; i < 2048; i += 256) {
      int r = i >> 7, k = i & 127;
      vch[(size_t)(nxg + r) * 256 + 2 * k] = Xs[r * 128 + k];
    }
    int cid = t & 63, wq = t >> 6;
    int m0 = 2 * cid + 1, m1 = 2 * cid + 129;
    float acc[4][2];
#pragma unroll
    for (int r = 0; r < 4; ++r) { acc[r][0] = 0.f; acc[r][1] = 0.f; }
    for (int ny = 0; ny < 128; ++ny) {
      float r0 = Rl[(m0 - 2 * ny) & 255];
      float r1 = Rl[(m1 - 2 * ny) & 255];
#pragma unroll
      for (int r = 0; r < 4; ++r) {
        float xv = Xs[(4 * wq + r) * 128 + ny];
        acc[r][0] += xv * r0;
        acc[r][1] += xv * r1;
      }
    }
#pragma unroll
    for (int r = 0; r < 4; ++r) {
      vch[(size_t)(nxg + 4 * wq + r) * 256 + m0] = acc[r][0];
      vch[(size_t)(nxg + 4 * wq + r) * 256 + m1] = acc[r][1];
    }
    return;
  }
  // ---- V02 / V12 (full-column path) ----
  {
    int vbid = bid - 320;
    const float* X = X2; float* V;
    int n1, n2, s, ch, nxg, colh;
    if (vbid < 128) {
      V = V02; n1 = 256; n2 = 64; s = 4;
      ch = vbid >> 3; nxg = ((vbid >> 1) & 3) * 16; colh = vbid & 1;
    } else {
      int w = vbid - 128;
      V = V12; n1 = 128; n2 = 64; s = 2;
      ch = w >> 2; nxg = (w & 3) * 16; colh = 0;
    }
    float* Rl = fsm;
    float* Xs = fsm + 256;
    for (int i = t; i < n1; i += 256) Rl[i] = rtab_val(n1, n2, i);
    const float4* xch4 =
        (const float4*)(X + (size_t)ch * n2 * n2 + (size_t)nxg * n2);
    int nx4 = (16 * n2) >> 2;
    for (int i = t; i < nx4; i += 256) ((float4*)Xs)[i] = xch4[i];
    __syncthreads();
    if (vbid == 0)
      for (int i = t; i < 256; i += 256) T02[i] = Rl[i];
    if (vbid == 128)
      for (int i = t; i < 128; i += 256) T12[i] = Rl[i];
    int myq = (t & 63) + colh * 128;
    int nxq = t >> 6;
    int mask = n1 - 1;
    float acc[4][2];
#pragma unroll
    for (int r = 0; r < 4; ++r)
#pragma unroll
      for (int c = 0; c < 2; ++c) acc[r][c] = 0.f;
    for (int ny = 0; ny < n2; ++ny) {
      float xv[4];
#pragma unroll
      for (int r = 0; r < 4; ++r) xv[r] = Xs[(4 * nxq + r) * n2 + ny];
#pragma unroll
      for (int c = 0; c < 2; ++c) {
        float rv = Rl[(myq + 64 * c - s * ny) & mask];
#pragma unroll
        for (int r = 0; r < 4; ++r) acc[r][c] += xv[r] * rv;
      }
    }
    float* vch = V + (size_t)ch * n2 * n1;
#pragma unroll
    for (int r = 0; r < 4; ++r)
      for (int c = 0; c < 2; ++c)
        vch[(size_t)(nxg + 4 * nxq + r) * n1 + myq + 64 * c] = acc[r][c];
  }
}

// k_main: u<640 fused U+corr (round-4 staged phase A); u in [640,1088)
// self-corr groups (moved here so k_front's zero-out block is race-free).
__global__ __launch_bounds__(256) void k_main(const float* __restrict__ X0,
                                              const float* __restrict__ X1,
                                              const float* __restrict__ X2,
                                              const float* __restrict__ V01,
                                              const float* __restrict__ V02,
                                              const float* __restrict__ V12,
                                              const float* __restrict__ P1p,
                                              const float* __restrict__ P2p,
                                              const float* __restrict__ T01,
                                              const float* __restrict__ T02,
                                              const float* __restrict__ T12,
                                              float* __restrict__ out) {
  __shared__ float sRl[256];
  __shared__ float sh[4864];      // Us 19*256 / epilogue (time-shared)
  __shared__ float Vs[2][2048];   // 8-row V tile, double-buffered (16 KB)
  int u = blockIdx.x;
  int t = threadIdx.x;
  int lane = t & 63;
  int wv = t >> 6;

  float accC[8][7];
#pragma unroll
  for (int i = 0; i < 8; ++i)
#pragma unroll
    for (int p = 0; p < 7; ++p) accC[i][p] = 0.f;

  int b, l2, base;

  if (u < 640) {
    // ================= fused U + corr =================
    const float* V; const float* Pp; const float* A1b; const float* T;
    int n1, n2, s, ch, chunk, nsp, lgn1; float inv;
    if (u < 256) {
      V = V01; Pp = P1p; nsp = 8; A1b = X0; n1 = 256; n2 = 128; s = 2;
      inv = 1.f / 16384.f; ch = u >> 4; chunk = u & 15; lgn1 = 8; base = 64;
      T = T01;
    } else if (u < 512) {
      int w = u - 256;
      V = V02; Pp = P2p; nsp = 4; A1b = X0; n1 = 256; n2 = 64; s = 4;
      inv = 1.f / 4096.f; ch = w >> 4; chunk = w & 15; lgn1 = 8; base = 128;
      T = T02;
    } else {
      int w = u - 512;
      V = V12; Pp = P2p; nsp = 4; A1b = X1; n1 = 128; n2 = 64; s = 2;
      inv = 1.f / 4096.f; ch = w >> 3; chunk = w & 7; lgn1 = 7; base = 256;
      T = T12;
    }
    int mask = n1 - 1;
    for (int i = t; i < n1; i += 256) sRl[i] = T[i];  // visible after tile-0 sync
    int mxg = chunk * 16;
    b = ch >> 3; l2 = ch & 7;
    const float* vch = V + (size_t)ch * n2 * n1;
    float Pv = 0.f;
    for (int i = 0; i < nsp; ++i) Pv += Pp[ch * nsp + i];
    float a = PI_F / (float)s;
    int per = 2 * s;

    // ---- Dirichlet-trivial rows: exact V-row copies (block-wide, up-front) ----
    if (n1 == 256) {
      if (s == 2) {
        for (int i = t; i < 640; i += 256) {
          int rl = 2 * (i >> 6), c4 = (i & 63) * 4;
          int mx = (mxg - 2 + rl) & 255;
          *(float4*)&sh[rl * 256 + c4] =
              *(const float4*)(vch + (size_t)(mx >> 1) * 256 + c4);
        }
      } else {
        for (int i = t; i < 320; i += 256) {
          int rl = 2 + 4 * (i >> 6), c4 = (i & 63) * 4;
          int mx = (mxg - 2 + rl) & 255;
          *(float4*)&sh[rl * 256 + c4] =
              *(const float4*)(vch + (size_t)(mx >> 2) * 256 + c4);
        }
      }
    } else {
      for (int i = t; i < 320; i += 256) {
        int rl = 2 * (i >> 5), c4 = (i & 31) * 4;
        int mx = (mxg - 2 + rl) & 127;
        *(float4*)&sh[rl * 128 + c4] =
            *(const float4*)(vch + (size_t)(mx >> 1) * 128 + c4);
      }
    }

    // ---- per-wave interp-row assignment ----
    int nr, rls[4];
    if (s == 2) {  // 9 rows: {1,3,5},{7,9},{11,13},{15,17}
      if (wv == 0)      { nr = 3; rls[0] = 1;  rls[1] = 3;  rls[2] = 5;  rls[3] = 1; }
      else if (wv == 1) { nr = 2; rls[0] = 7;  rls[1] = 9;  rls[2] = 7;  rls[3] = 7; }
      else if (wv == 2) { nr = 2; rls[0] = 11; rls[1] = 13; rls[2] = 11; rls[3] = 11; }
      else              { nr = 2; rls[0] = 15; rls[1] = 17; rls[2] = 15; rls[3] = 15; }
    } else {       // 14 rows: {0,1,3,4},{5,7,8,9},{11,12,13},{15,16,17}
      if (wv == 0)      { nr = 4; rls[0] = 0;  rls[1] = 1;  rls[2] = 3;  rls[3] = 4; }
      else if (wv == 1) { nr = 4; rls[0] = 5;  rls[1] = 7;  rls[2] = 8;  rls[3] = 9; }
      else if (wv == 2) { nr = 3; rls[0] = 11; rls[1] = 12; rls[2] = 13; rls[3] = 11; }
      else              { nr = 3; rls[0] = 15; rls[1] = 16; rls[2] = 17; rls[3] = 15; }
    }
    int bj[4];
#pragma unroll
    for (int j = 0; j < 4; ++j) bj[j] = (mxg - 2 + rls[j]) & mask;

    // ---- phase A: staged tap loop (8-row tiles, double-buffered) ----
    const float4* vp4 = (const float4*)vch;
    if (n1 == 256) {
      int ntl = n2 >> 3;  // 16 or 8 tiles
      for (int i = t; i < 512; i += 256) ((float4*)Vs[0])[i] = vp4[i];
      __syncthreads();
      float4 acc[4];
#pragma unroll
      for (int j = 0; j < 4; ++j) acc[j] = make_float4(0.f, 0.f, 0.f, 0.f);
      for (int tl = 0; tl < ntl; ++tl) {
        float4 stg0, stg1;
        bool has = (tl + 1 < ntl);
        if (has) {
          stg0 = vp4[(size_t)(tl + 1) * 512 + t];
          stg1 = vp4[(size_t)(tl + 1) * 512 + 256 + t];
        }
        const float* Vc = Vs[tl & 1];
        int tb = tl * 8;
#pragma unroll
        for (int kk = 0; kk < 8; ++kk) {
          float4 vv = *(const float4*)&Vc[kk * 256 + 4 * lane];
          int ss = s * (tb + kk);
#pragma unroll
          for (int j = 0; j < 4; ++j)
            if (j < nr) {
              float rv = sRl[(bj[j] - ss) & 255];
              acc[j].x += rv * vv.x;
              acc[j].y += rv * vv.y;
              acc[j].z += rv * vv.z;
              acc[j].w += rv * vv.w;
            }
        }
        if (has) {
          float4* d = (float4*)Vs[(tl & 1) ^ 1];
          d[t] = stg0;
          d[256 + t] = stg1;
        }
        __syncthreads();
      }
      float smy[4];
#pragma unroll
      for (int j = 0; j < 4; ++j)
        smy[j] = sinf(a * (float)((4 * lane + j) & (per - 1)));
#pragma unroll
      for (int j = 0; j < 4; ++j)
        if (j < nr) {
          float q = inv * sinf(a * (float)(bj[j] & (per - 1))) * Pv;
          float4 o = acc[j];
          o.x -= q * smy[0];
          o.y -= q * smy[1];
          o.z -= q * smy[2];
          o.w -= q * smy[3];
          *(float4*)&sh[rls[j] * 256 + 4 * lane] = o;
        }
    } else {  // n1 == 128, s = 2
      for (int i = t; i < 256; i += 256) ((float4*)Vs[0])[i] = vp4[i];
      __syncthreads();
      float2 acc[4];
#pragma unroll
      for (int j = 0; j < 4; ++j) acc[j] = make_float2(0.f, 0.f);
      for (int tl = 0; tl < 8; ++tl) {
        float4 stg0;
        bool has = (tl + 1 < 8);
        if (has) stg0 = vp4[(size_t)(tl + 1) * 256 + t];
        const float* Vc = Vs[tl & 1];
        int tb = tl * 8;
#pragma unroll
        for (int kk = 0; kk < 8; ++kk) {
          float2 vv = *(const float2*)&Vc[kk * 128 + 2 * lane];
          int ss = 2 * (tb + kk);
#pragma unroll
          for (int j = 0; j < 4; ++j)
            if (j < nr) {
              float rv = sRl[(bj[j] - ss) & 127];
              acc[j].x += rv * vv.x;
              acc[j].y += rv * vv.y;
            }
        }
        if (has) ((float4*)Vs[(tl & 1) ^ 1])[t] = stg0;
        __syncthreads();
      }
      const float a2 = PI_F * 0.5f;
      float smy0 = sinf(a2 * (float)((2 * lane) & 3));
      float smy1 = sinf(a2 * (float)((2 * lane + 1) & 3));
#pragma unroll
      for (int j = 0; j < 4; ++j)
        if (j < nr) {
          float q = inv * sinf(a2 * (float)(bj[j] & 3)) * Pv;
          float2 o = acc[j];
          o.x -= q * smy0;
          o.y -= q * smy1;
          *(float2*)&sh[rls[j] * 128 + 2 * lane] = o;
        }
    }
    __syncthreads();

    // ---- phase B: corr of A1 rows [mxg, mxg+16) against Us (LDS = sh) ----
    int lgtpr = lgn1 - 2;
    int tpr = 1 << lgtpr;
    int rif = 256 >> lgtpr;
    int rid = t >> lgtpr;
    int cid2 = t & (tpr - 1);
    int ty = cid2 * 4;
    int tym = (ty - 4) & mask;
    int n1sq = n1 * n1;
    const float* A1 = A1b + (size_t)(b * 8) * n1sq;
    for (int rr = 0; rr < 16; rr += rif) {
      int ri = rr + rid;
      const float* r0 = &sh[(ri + 2) * n1];
      const float* r1 = &sh[(ri + 1) * n1];
      const float* r2 = &sh[ri * n1];
      const float* r3 = &sh[(ri + 3) * n1];
      float4 a0 = *(const float4*)(r0 + tym);
      float4 b0 = *(const float4*)(r0 + ty);
      float4 a1 = *(const float4*)(r1 + tym);
      float4 b1 = *(const float4*)(r1 + ty);
      float4 b2 = *(const float4*)(r2 + ty);
      float4 a3 = *(const float4*)(r3 + tym);
      float4 b3 = *(const float4*)(r3 + ty);
      const float* rA = A1 + (size_t)(mxg + ri) * n1 + ty;
#pragma unroll
      for (int l1 = 0; l1 < 8; ++l1) {
        float4 xv = *(const float4*)(rA + (size_t)l1 * n1sq);
        accC[l1][0] += xv.x * b0.x + xv.y * b0.y + xv.z * b0.z + xv.w * b0.w;
        accC[l1][1] += xv.x * a0.w + xv.y * b0.x + xv.z * b0.y + xv.w * b0.z;
        accC[l1][2] += xv.x * a0.z + xv.y * a0.w + xv.z * b0.x + xv.w * b0.y;
        accC[l1][3] += xv.x * b1.x + xv.y * b1.y + xv.z * b1.z + xv.w * b1.w;
        accC[l1][4] += xv.x * a1.w + xv.y * b1.x + xv.z * b1.y + xv.w * b1.z;
        accC[l1][5] += xv.x * b2.x + xv.y * b2.y + xv.z * b2.z + xv.w * b2.w;
        accC[l1][6] += xv.x * a3.w + xv.y * b3.x + xv.z * b3.y + xv.w * b3.z;
      }
    }
  } else {
    // ================= self-corr (groups 0,3,5) =================
    int w = u - 640;
    const float* Ab; int loc, lgn1, lgc;
    if (w < 256)      { loc = w;       Ab = X0; lgn1 = 8; lgc = 4; base = 0;   }
    else if (w < 384) { loc = w - 256; Ab = X1; lgn1 = 7; lgc = 3; base = 192; }
    else              { loc = w - 384; Ab = X2; lgn1 = 6; lgc = 2; base = 320; }
    int n1 = 1 << lgn1;
    int mask = n1 - 1;
    int n1sq = n1 * n1;
    int chunk = loc & ((1 << lgc) - 1);
    int bl2 = loc >> lgc;
    b = bl2 >> 3; l2 = bl2 & 7;
    const float* A1 = Ab + (size_t)(b * 8) * n1sq;
    const float* A2 = Ab + (size_t)(b * 8 + l2) * n1sq;
    int lgtpr = lgn1 - 2;
    int tpr = 1 << lgtpr;
    int rif = 256 >> lgtpr;
    int rid = t >> lgtpr;
    int cid2 = t & (tpr - 1);
    int ty = cid2 * 4;
    int tym = (ty - 4) & mask;
    for (int rr = 0; rr < 16; rr += rif) {
      int row = chunk * 16 + rr + rid;
      const float* r0 = A2 + (size_t)row * n1;
      const float* r1 = A2 + (size_t)((row - 1) & mask) * n1;
      const float* r2 = A2 + (size_t)((row - 2) & mask) * n1;
      const float* r3 = A2 + (size_t)((row + 1) & mask) * n1;
      float4 a0 = *(const float4*)(r0 + tym);
      float4 b0 = *(const float4*)(r0 + ty);
      float4 a1 = *(const float4*)(r1 + tym);
      float4 b1 = *(const float4*)(r1 + ty);
      float4 b2 = *(const float4*)(r2 + ty);
      float4 a3 = *(const float4*)(r3 + tym);
      float4 b3 = *(const float4*)(r3 + ty);
      const float* rA = A1 + (size_t)row * n1 + ty;
#pragma unroll
      for (int l1 = 0; l1 < 8; ++l1) {
        float4 xv = *(const float4*)(rA + (size_t)l1 * n1sq);
        accC[l1][0] += xv.x * b0.x + xv.y * b0.y + xv.z * b0.z + xv.w * b0.w;
        accC[l1][1] += xv.x * a0.w + xv.y * b0.x + xv.z * b0.y + xv.w * b0.z;
        accC[l1][2] += xv.x * a0.z + xv.y * a0.w + xv.z * b0.x + xv.w * b0.y;
        accC[l1][3] += xv.x * b1.x + xv.y * b1.y + xv.z * b1.z + xv.w * b1.w;
        accC[l1][4] += xv.x * a1.w + xv.y * b1.x + xv.z * b1.y + xv.w * b1.z;
        accC[l1][5] += xv.x * b2.x + xv.y * b2.y + xv.z * b2.z + xv.w * b2.w;
        accC[l1][6] += xv.x * a3.w + xv.y * b3.x + xv.z * b3.y + xv.w * b3.z;
      }
    }
  }

  // ---- shared epilogue: 2-shfl fold + LDS transpose (stride 60) ----
  float* af = &accC[0][0];
#pragma unroll
  for (int j = 0; j < 56; ++j) {
    float v = af[j];
    v += __shfl_down(v, 32, 64);
    v += __shfl_down(v, 16, 64);
    af[j] = v;
  }
  __syncthreads();  // phase-B Us reads done before epilogue overwrites region
  if (lane < 16) {
    float* rowp = sh + (wv * 16 + lane) * 60;
#pragma unroll
    for (int j = 0; j < 14; ++j)
      *(float4*)&rowp[4 * j] =
          make_float4(af[4 * j], af[4 * j + 1], af[4 * j + 2], af[4 * j + 3]);
  }
  __syncthreads();
  if (t < 224) {
    int v = t >> 2, q = t & 3;
    float s2 = 0.f;
#pragma unroll
    for (int i = 0; i < 16; ++i) s2 += sh[(q * 16 + i) * 60 + v];
    s2 += __shfl_down(s2, 2, 64);
    s2 += __shfl_down(s2, 1, 64);
    if (q == 0) {
      int l1o = v / 7, p = v % 7;
      atomicAdd(&out[((size_t)b * 384 + base + l1o * 8 + l2) * 7 + p], s2);
    }
  }
}

extern "C" void kernel_launch(void* const* d_in, const int* in_sizes, int n_in,
                              void* d_out, int out_size, void* d_ws, size_t ws_size,
                              hipStream_t stream) {
  const float* X0 = (const float*)d_in[0];  // [2,8,256,256]
  const float* X1 = (const float*)d_in[1];  // [2,8,128,128]
  const float* X2 = (const float*)d_in[2];  // [2,8,64,64]
  float* out = (float*)d_out;               // [2,384,7]
  float* ws = (float*)d_ws;

  float* V01 = ws + 2359296;
  float* V02 = ws + 2883584;
  float* V12 = ws + 3145728;
  float* P1p = ws + 3276800;
  float* P2p = ws + 3276928;
  float* T01 = ws + 3276992;
  float* T02 = ws + 3277248;
  float* T12 = ws + 3277504;

  k_front<<<513, 256, 0, stream>>>(X0, X1, X2, P1p, P2p, V01, V02, V12, T01,
                                   T02, T12, out);
  k_main<<<1088, 256, 0, stream>>>(X0, X1, X2, V01, V02, V12, P1p, P2p, T01,
                                   T02, T12, out);
}

// Round 6
// 94.929 us; speedup vs baseline: 1.1297x; 1.1297x over previous
//
#include <hip/hip_runtime.h>

#define PI_D 3.14159265358979323846
#define PI_F 3.14159265358979323846f

// ---- workspace layout (floats) ----
// V01 @ 2359296 : 524288   V02 @ 2883584 : 262144   V12 @ 3145728 : 131072
// P1p @ 3276800 : 128      P2p @ 3276928 : 64
// T01 @ 3276992 : 256      T02 @ 3277248 : 256      T12 @ 3277504 : 128

// Dirichlet tap, f64 (computed in k_front; k_main loads precomputed tables).
// Analytically: Rl[0] = 1 and Rl[t] = 0 for t % s == 0 (t != 0, s = n1/n2).
__device__ inline float rtab_val(int n, int m2, int t) {
  if (t == 0) return 1.0f;
  double th = PI_D * (double)t / (double)n;
  double v = sin(th * (double)(m2 - 1)) / sin(th) + cos(th * (double)m2);
  return (float)(v / (double)m2);
}

// k_front: bid 0..191 P partials; 192..319 V01 (odd cols computed, even cols
// exact X1 copies; bid 192 writes T01); 320..447 V02 (bid 320 writes T02);
// 448..511 V12 (bid 448 writes T12); 512 zeroes out. No atomics here, so the
// zero-block is race-free (all atomic writers live in k_main).
__global__ __launch_bounds__(256) void k_front(
    const float* __restrict__ X0, const float* __restrict__ X1,
    const float* __restrict__ X2, float* __restrict__ P1p,
    float* __restrict__ P2p, float* __restrict__ V01, float* __restrict__ V02,
    float* __restrict__ V12, float* __restrict__ T01, float* __restrict__ T02,
    float* __restrict__ T12, float* __restrict__ out) {
  __shared__ float fsm[2304];
  int bid = blockIdx.x;
  int t = threadIdx.x;
  if (bid == 512) {
    for (int i = t; i < 5376; i += 256) out[i] = 0.f;
    return;
  }
  if (bid < 192) {
    // ---- P partials ----
    const float* X; float* P; int lg, nsp, idx0;
    if (bid < 128) { X = X1; P = P1p; lg = 7; nsp = 8; idx0 = bid; }
    else           { X = X2; P = P2p; lg = 6; nsp = 4; idx0 = bid - 128; }
    int ch = idx0 / nsp, split = idx0 % nsp;
    int n = 1 << lg;
    int total = n * n;
    int chunk = total / nsp;
    int b0 = split * chunk;
    const float* x = X + (size_t)ch * total + b0;
    float s = 0.f;
    for (int i = t; i < chunk; i += 256) {
      int idx = b0 + i;
      float v = x[i];
      s += (((idx >> lg) ^ idx) & 1) ? -v : v;
    }
#pragma unroll
    for (int off = 32; off > 0; off >>= 1) s += __shfl_down(s, off, 64);
    __shared__ float red[4];
    if ((t & 63) == 0) red[t >> 6] = s;
    __syncthreads();
    if (t == 0) P[ch * nsp + split] = red[0] + red[1] + red[2] + red[3];
    return;
  }
  if (bid < 320) {
    // ---- V01: compute odd columns only; even columns copy X1 ----
    int idx = bid - 192;
    int ch = idx >> 3, nxg = (idx & 7) * 16;
    float* Rl = fsm;
    float* Xs = fsm + 256;
    for (int i = t; i < 256; i += 256) Rl[i] = rtab_val(256, 128, i);
    const float4* xch4 =
        (const float4*)(X1 + (size_t)ch * 16384 + (size_t)nxg * 128);
    for (int i = t; i < 512; i += 256) ((float4*)Xs)[i] = xch4[i];
    __syncthreads();
    if (idx == 0)
      for (int i = t; i < 256; i += 256) T01[i] = Rl[i];
    float* vch = V01 + (size_t)ch * 128 * 256;
    for (int i = t; i < 2048; i += 256) {
      int r = i >> 7, k = i & 127;
      vch[(size_t)(nxg + r) * 256 + 2 * k] = Xs[r * 128 + k];
    }
    int cid = t & 63, wq = t >> 6;
    int m0 = 2 * cid + 1, m1 = 2 * cid + 129;
    float acc[4][2];
#pragma unroll
    for (int r = 0; r < 4; ++r) { acc[r][0] = 0.f; acc[r][1] = 0.f; }
    for (int ny = 0; ny < 128; ++ny) {
      float r0 = Rl[(m0 - 2 * ny) & 255];
      float r1 = Rl[(m1 - 2 * ny) & 255];
#pragma unroll
      for (int r = 0; r < 4; ++r) {
        float xv = Xs[(4 * wq + r) * 128 + ny];
        acc[r][0] += xv * r0;
        acc[r][1] += xv * r1;
      }
    }
#pragma unroll
    for (int r = 0; r < 4; ++r) {
      vch[(size_t)(nxg + 4 * wq + r) * 256 + m0] = acc[r][0];
      vch[(size_t)(nxg + 4 * wq + r) * 256 + m1] = acc[r][1];
    }
    return;
  }
  // ---- V02 / V12 (full-column path) ----
  {
    int vbid = bid - 320;
    const float* X = X2; float* V;
    int n1, n2, s, ch, nxg, colh;
    if (vbid < 128) {
      V = V02; n1 = 256; n2 = 64; s = 4;
      ch = vbid >> 3; nxg = ((vbid >> 1) & 3) * 16; colh = vbid & 1;
    } else {
      int w = vbid - 128;
      V = V12; n1 = 128; n2 = 64; s = 2;
      ch = w >> 2; nxg = (w & 3) * 16; colh = 0;
    }
    float* Rl = fsm;
    float* Xs = fsm + 256;
    for (int i = t; i < n1; i += 256) Rl[i] = rtab_val(n1, n2, i);
    const float4* xch4 =
        (const float4*)(X + (size_t)ch * n2 * n2 + (size_t)nxg * n2);
    int nx4 = (16 * n2) >> 2;
    for (int i = t; i < nx4; i += 256) ((float4*)Xs)[i] = xch4[i];
    __syncthreads();
    if (vbid == 0)
      for (int i = t; i < 256; i += 256) T02[i] = Rl[i];
    if (vbid == 128)
      for (int i = t; i < 128; i += 256) T12[i] = Rl[i];
    int myq = (t & 63) + colh * 128;
    int nxq = t >> 6;
    int mask = n1 - 1;
    float acc[4][2];
#pragma unroll
    for (int r = 0; r < 4; ++r)
#pragma unroll
      for (int c = 0; c < 2; ++c) acc[r][c] = 0.f;
    for (int ny = 0; ny < n2; ++ny) {
      float xv[4];
#pragma unroll
      for (int r = 0; r < 4; ++r) xv[r] = Xs[(4 * nxq + r) * n2 + ny];
#pragma unroll
      for (int c = 0; c < 2; ++c) {
        float rv = Rl[(myq + 64 * c - s * ny) & mask];
#pragma unroll
        for (int r = 0; r < 4; ++r) acc[r][c] += xv[r] * rv;
      }
    }
    float* vch = V + (size_t)ch * n2 * n1;
#pragma unroll
    for (int r = 0; r < 4; ++r)
      for (int c = 0; c < 2; ++c)
        vch[(size_t)(nxg + 4 * nxq + r) * n1 + myq + 64 * c] = acc[r][c];
  }
}

// k_main: 1088 blocks, unified structure. Every block builds a 19-row window
// in sh then runs the same phase-B loop.
//   u < 640      fused: window = Dirichlet-interp of V (staged 4-row tiles,
//                double-buffered Vs, 8 KB) + exact V-row copies.
//   u in [640,1088) self-corr: window = direct coalesced stage of A2 rows.
// LDS = 1K (sRl) + 19K (sh) + 8K (Vs) = 28 KB -> 5 blocks/CU.
__global__ __launch_bounds__(256) void k_main(const float* __restrict__ X0,
                                              const float* __restrict__ X1,
                                              const float* __restrict__ X2,
                                              const float* __restrict__ V01,
                                              const float* __restrict__ V02,
                                              const float* __restrict__ V12,
                                              const float* __restrict__ P1p,
                                              const float* __restrict__ P2p,
                                              const float* __restrict__ T01,
                                              const float* __restrict__ T02,
                                              const float* __restrict__ T12,
                                              float* __restrict__ out) {
  __shared__ float sRl[256];
  __shared__ float sh[4864];     // 19-row window / epilogue (time-shared)
  __shared__ float Vs[2][1024];  // 4-row V tile, double-buffered (8 KB)
  int u = blockIdx.x;
  int t = threadIdx.x;
  int lane = t & 63;
  int wv = t >> 6;

  int b, l2, base, lgn1, mxg;
  const float* A1b;

  if (u < 640) {
    // ================= fused: interp window =================
    const float* V; const float* Pp; const float* T;
    int n1, n2, s, ch, chunk, nsp; float inv;
    if (u < 256) {
      V = V01; Pp = P1p; nsp = 8; A1b = X0; n1 = 256; n2 = 128; s = 2;
      inv = 1.f / 16384.f; ch = u >> 4; chunk = u & 15; lgn1 = 8; base = 64;
      T = T01;
    } else if (u < 512) {
      int w = u - 256;
      V = V02; Pp = P2p; nsp = 4; A1b = X0; n1 = 256; n2 = 64; s = 4;
      inv = 1.f / 4096.f; ch = w >> 4; chunk = w & 15; lgn1 = 8; base = 128;
      T = T02;
    } else {
      int w = u - 512;
      V = V12; Pp = P2p; nsp = 4; A1b = X1; n1 = 128; n2 = 64; s = 2;
      inv = 1.f / 4096.f; ch = w >> 3; chunk = w & 7; lgn1 = 7; base = 256;
      T = T12;
    }
    int mask = n1 - 1;
    for (int i = t; i < n1; i += 256) sRl[i] = T[i];  // visible after tile-0 sync
    mxg = chunk * 16;
    b = ch >> 3; l2 = ch & 7;
    const float* vch = V + (size_t)ch * n2 * n1;
    float Pv = 0.f;
    for (int i = 0; i < nsp; ++i) Pv += Pp[ch * nsp + i];
    float a = PI_F / (float)s;
    int per = 2 * s;

    // ---- Dirichlet-trivial rows: exact V-row copies (block-wide, up-front) ----
    if (n1 == 256) {
      if (s == 2) {
        for (int i = t; i < 640; i += 256) {
          int rl = 2 * (i >> 6), c4 = (i & 63) * 4;
          int mx = (mxg - 2 + rl) & 255;
          *(float4*)&sh[rl * 256 + c4] =
              *(const float4*)(vch + (size_t)(mx >> 1) * 256 + c4);
        }
      } else {
        for (int i = t; i < 320; i += 256) {
          int rl = 2 + 4 * (i >> 6), c4 = (i & 63) * 4;
          int mx = (mxg - 2 + rl) & 255;
          *(float4*)&sh[rl * 256 + c4] =
              *(const float4*)(vch + (size_t)(mx >> 2) * 256 + c4);
        }
      }
    } else {
      for (int i = t; i < 320; i += 256) {
        int rl = 2 * (i >> 5), c4 = (i & 31) * 4;
        int mx = (mxg - 2 + rl) & 127;
        *(float4*)&sh[rl * 128 + c4] =
            *(const float4*)(vch + (size_t)(mx >> 1) * 128 + c4);
      }
    }

    // ---- per-wave interp-row assignment ----
    int nr, rls[4];
    if (s == 2) {  // 9 rows: {1,3,5},{7,9},{11,13},{15,17}
      if (wv == 0)      { nr = 3; rls[0] = 1;  rls[1] = 3;  rls[2] = 5;  rls[3] = 1; }
      else if (wv == 1) { nr = 2; rls[0] = 7;  rls[1] = 9;  rls[2] = 7;  rls[3] = 7; }
      else if (wv == 2) { nr = 2; rls[0] = 11; rls[1] = 13; rls[2] = 11; rls[3] = 11; }
      else              { nr = 2; rls[0] = 15; rls[1] = 17; rls[2] = 15; rls[3] = 15; }
    } else {       // 14 rows: {0,1,3,4},{5,7,8,9},{11,12,13},{15,16,17}
      if (wv == 0)      { nr = 4; rls[0] = 0;  rls[1] = 1;  rls[2] = 3;  rls[3] = 4; }
      else if (wv == 1) { nr = 4; rls[0] = 5;  rls[1] = 7;  rls[2] = 8;  rls[3] = 9; }
      else if (wv == 2) { nr = 3; rls[0] = 11; rls[1] = 12; rls[2] = 13; rls[3] = 11; }
      else              { nr = 3; rls[0] = 15; rls[1] = 16; rls[2] = 17; rls[3] = 15; }
    }
    int bj[4];
#pragma unroll
    for (int j = 0; j < 4; ++j) bj[j] = (mxg - 2 + rls[j]) & mask;

    // ---- staged tap loop: 4-row tiles, double-buffered ----
    const float4* vp4 = (const float4*)vch;
    if (n1 == 256) {
      int ntl = n2 >> 2;  // 32 or 16 tiles
      ((float4*)Vs[0])[t] = vp4[t];
      __syncthreads();
      float4 acc[4];
#pragma unroll
      for (int j = 0; j < 4; ++j) acc[j] = make_float4(0.f, 0.f, 0.f, 0.f);
      for (int tl = 0; tl < ntl; ++tl) {
        float4 stg;
        bool has = (tl + 1 < ntl);
        if (has) stg = vp4[(size_t)(tl + 1) * 256 + t];
        const float* Vc = Vs[tl & 1];
#pragma unroll
        for (int kk = 0; kk < 4; ++kk) {
          float4 vv = *(const float4*)&Vc[kk * 256 + 4 * lane];
          int ss = s * (4 * tl + kk);
#pragma unroll
          for (int j = 0; j < 4; ++j)
            if (j < nr) {
              float rv = sRl[(bj[j] - ss) & 255];
              acc[j].x += rv * vv.x;
              acc[j].y += rv * vv.y;
              acc[j].z += rv * vv.z;
              acc[j].w += rv * vv.w;
            }
        }
        if (has) ((float4*)Vs[(tl & 1) ^ 1])[t] = stg;
        __syncthreads();
      }
      float smy[4];
#pragma unroll
      for (int j = 0; j < 4; ++j)
        smy[j] = sinf(a * (float)((4 * lane + j) & (per - 1)));
#pragma unroll
      for (int j = 0; j < 4; ++j)
        if (j < nr) {
          float q = inv * sinf(a * (float)(bj[j] & (per - 1))) * Pv;
          float4 o = acc[j];
          o.x -= q * smy[0];
          o.y -= q * smy[1];
          o.z -= q * smy[2];
          o.w -= q * smy[3];
          *(float4*)&sh[rls[j] * 256 + 4 * lane] = o;
        }
    } else {  // n1 == 128, s = 2, n2 = 64 -> 16 tiles of 128 float4
      if (t < 128) ((float4*)Vs[0])[t] = vp4[t];
      __syncthreads();
      float2 acc[4];
#pragma unroll
      for (int j = 0; j < 4; ++j) acc[j] = make_float2(0.f, 0.f);
      for (int tl = 0; tl < 16; ++tl) {
        float4 stg;
        bool has = (tl + 1 < 16) && (t < 128);
        if (has) stg = vp4[(size_t)(tl + 1) * 128 + t];
        const float* Vc = Vs[tl & 1];
#pragma unroll
        for (int kk = 0; kk < 4; ++kk) {
          float2 vv = *(const float2*)&Vc[kk * 128 + 2 * lane];
          int ss = 2 * (4 * tl + kk);
#pragma unroll
          for (int j = 0; j < 4; ++j)
            if (j < nr) {
              float rv = sRl[(bj[j] - ss) & 127];
              acc[j].x += rv * vv.x;
              acc[j].y += rv * vv.y;
            }
        }
        if (has) ((float4*)Vs[(tl & 1) ^ 1])[t] = stg;
        __syncthreads();
      }
      const float a2 = PI_F * 0.5f;
      float smy0 = sinf(a2 * (float)((2 * lane) & 3));
      float smy1 = sinf(a2 * (float)((2 * lane + 1) & 3));
#pragma unroll
      for (int j = 0; j < 4; ++j)
        if (j < nr) {
          float q = inv * sinf(a2 * (float)(bj[j] & 3)) * Pv;
          float2 o = acc[j];
          o.x -= q * smy0;
          o.y -= q * smy1;
          *(float2*)&sh[rls[j] * 128 + 2 * lane] = o;
        }
    }
  } else {
    // ================= self-corr: stage A2 window directly =================
    int w = u - 640;
    const float* Ab; int loc, lgc;
    if (w < 256)      { loc = w;       Ab = X0; lgn1 = 8; lgc = 4; base = 0;   }
    else if (w < 384) { loc = w - 256; Ab = X1; lgn1 = 7; lgc = 3; base = 192; }
    else              { loc = w - 384; Ab = X2; lgn1 = 6; lgc = 2; base = 320; }
    int n1 = 1 << lgn1;
    int mask = n1 - 1;
    int n1sq = n1 * n1;
    int chunk = loc & ((1 << lgc) - 1);
    int bl2 = loc >> lgc;
    b = bl2 >> 3; l2 = bl2 & 7;
    A1b = Ab;
    const float* A2 = Ab + (size_t)(b * 8 + l2) * n1sq;
    mxg = chunk * 16;
    // stage 19 rows [mxg-2, mxg+17) of A2 into sh (coalesced float4)
    int nst = (19 * n1) >> 2;
    int l2n1 = lgn1 - 2;  // log2(n1/4)
    for (int i = t; i < nst; i += 256) {
      int rl = i >> l2n1;
      int c4 = (i & ((n1 >> 2) - 1)) * 4;
      int src = (mxg - 2 + rl) & mask;
      *(float4*)&sh[rl * n1 + c4] = *(const float4*)(A2 + (size_t)src * n1 + c4);
    }
  }
  __syncthreads();

  // ---- unified phase B: corr of A1 rows [mxg, mxg+16) against sh window ----
  float accC[8][7];
#pragma unroll
  for (int i = 0; i < 8; ++i)
#pragma unroll
    for (int p = 0; p < 7; ++p) accC[i][p] = 0.f;
  {
    int n1 = 1 << lgn1;
    int mask = n1 - 1;
    int n1sq = n1 * n1;
    int lgtpr = lgn1 - 2;
    int tpr = 1 << lgtpr;
    int rif = 256 >> lgtpr;
    int rid = t >> lgtpr;
    int cid2 = t & (tpr - 1);
    int ty = cid2 * 4;
    int tym = (ty - 4) & mask;
    const float* A1 = A1b + (size_t)(b * 8) * n1sq;
    for (int rr = 0; rr < 16; rr += rif) {
      int ri = rr + rid;
      const float* r0 = &sh[(ri + 2) * n1];
      const float* r1 = &sh[(ri + 1) * n1];
      const float* r2 = &sh[ri * n1];
      const float* r3 = &sh[(ri + 3) * n1];
      float4 a0 = *(const float4*)(r0 + tym);
      float4 b0 = *(const float4*)(r0 + ty);
      float4 a1 = *(const float4*)(r1 + tym);
      float4 b1 = *(const float4*)(r1 + ty);
      float4 b2 = *(const float4*)(r2 + ty);
      float4 a3 = *(const float4*)(r3 + tym);
      float4 b3 = *(const float4*)(r3 + ty);
      const float* rA = A1 + (size_t)(mxg + ri) * n1 + ty;
#pragma unroll
      for (int l1 = 0; l1 < 8; ++l1) {
        float4 xv = *(const float4*)(rA + (size_t)l1 * n1sq);
        accC[l1][0] += xv.x * b0.x + xv.y * b0.y + xv.z * b0.z + xv.w * b0.w;
        accC[l1][1] += xv.x * a0.w + xv.y * b0.x + xv.z * b0.y + xv.w * b0.z;
        accC[l1][2] += xv.x * a0.z + xv.y * a0.w + xv.z * b0.x + xv.w * b0.y;
        accC[l1][3] += xv.x * b1.x + xv.y * b1.y + xv.z * b1.z + xv.w * b1.w;
        accC[l1][4] += xv.x * a1.w + xv.y * b1.x + xv.z * b1.y + xv.w * b1.z;
        accC[l1][5] += xv.x * b2.x + xv.y * b2.y + xv.z * b2.z + xv.w * b2.w;
        accC[l1][6] += xv.x * a3.w + xv.y * b3.x + xv.z * b3.y + xv.w * b3.z;
      }
    }
  }

  // ---- epilogue: 2-shfl fold + LDS transpose (stride 60) ----
  float* af = &accC[0][0];
#pragma unroll
  for (int j = 0; j < 56; ++j) {
    float v = af[j];
    v += __shfl_down(v, 32, 64);
    v += __shfl_down(v, 16, 64);
    af[j] = v;
  }
  __syncthreads();  // phase-B window reads done before epilogue overwrites sh
  if (lane < 16) {
    float* rowp = sh + (wv * 16 + lane) * 60;
#pragma unroll
    for (int j = 0; j < 14; ++j)
      *(float4*)&rowp[4 * j] =
          make_float4(af[4 * j], af[4 * j + 1], af[4 * j + 2], af[4 * j + 3]);
  }
  __syncthreads();
  if (t < 224) {
    int v = t >> 2, q = t & 3;
    float s2 = 0.f;
#pragma unroll
    for (int i = 0; i < 16; ++i) s2 += sh[(q * 16 + i) * 60 + v];
    s2 += __shfl_down(s2, 2, 64);
    s2 += __shfl_down(s2, 1, 64);
    if (q == 0) {
      int l1o = v / 7, p = v % 7;
      atomicAdd(&out[((size_t)b * 384 + base + l1o * 8 + l2) * 7 + p], s2);
    }
  }
}

extern "C" void kernel_launch(void* const* d_in, const int* in_sizes, int n_in,
                              void* d_out, int out_size, void* d_ws, size_t ws_size,
                              hipStream_t stream) {
  const float* X0 = (const float*)d_in[0];  // [2,8,256,256]
  const float* X1 = (const float*)d_in[1];  // [2,8,128,128]
  const float* X2 = (const float*)d_in[2];  // [2,8,64,64]
  float* out = (float*)d_out;               // [2,384,7]
  float* ws = (float*)d_ws;

  float* V01 = ws + 2359296;
  float* V02 = ws + 2883584;
  float* V12 = ws + 3145728;
  float* P1p = ws + 3276800;
  float* P2p = ws + 3276928;
  float* T01 = ws + 3276992;
  float* T02 = ws + 3277248;
  float* T12 = ws + 3277504;

  k_front<<<513, 256, 0, stream>>>(X0, X1, X2, P1p, P2p, V01, V02, V12, T01,
                                   T02, T12, out);
  k_main<<<1088, 256, 0, stream>>>(X0, X1, X2, V01, V02, V12, P1p, P2p, T01,
                                   T02, T12, out);
}